// Round 10
// baseline (3961.040 us; speedup 1.0000x reference)
//
#include <hip/hip_runtime.h>

// ---------------------------------------------------------------------------
// GCN 3-layer forward. CSR-gather + bf16 MFMA GEMM.
// R2: atomic-free CSR build (LDS-ranked 2-level counting sort).
// R3-R6: gather<128> floor = 61us static (per-CU MSHR line-throughput bound).
//     dis[src] folded into GEMM epilogue.
// R7: CHUNK 2048 + 512-thr finalize — 435us. R8: coop grid.sync — 13x
//     REGRESSION (~100us/sync across 8 XCDs), reverted. R9: x->bf16 fused
//     into GEMM1 (AF32) — neutral, kept (one fewer pass).
// R10: (a) persistent-wave dynamic gather (global-atomic work counter;
//          fixes Poisson-degree tail imbalance seen as 70% occupancy);
//      (b) scan_phase2 merged into scan_phase3 (each block re-scans bsums
//          in LDS; removes a 1-block whole-GPU-idle launch);
//      (c) prep_w fused into bin_hist grid. Launches 13 -> 11.
// d_ws layout (max ~84 MB used; 119.2 MB proven safe):
//   [1 MB)   dis: N floats
//   [1472 KB) ctr: 3 ints (dynamic gather work counters)
//   [1.5 MB) bsums: up to 1024 ints
//   [1.6 MB) row_start: (N+1) ints
//   [2.5 MB) csr: E x int2 {src, ew*dis[dst] as float}  (12.8 MB)
//   [15.5MB) Wt1 bf16 [128][128]; Wt2; Wt3 [64][128]
//   [16 MB)  bufA: N*128 bf16 xw' (25.6 MB)
//   [42 MB)  hbf: N*128 bf16 (h1_bf16, then h2_bf16)
//   [68 MB)  mat: NB x NBLK ints (bucket-major count/offset matrix, 2.45 MB)
//   [71 MB)  binned: E x int2 {src | dstlow<<17, ew}  (12.8 MB, ends 83.8 MB)
// ---------------------------------------------------------------------------

typedef __attribute__((ext_vector_type(8))) short bf16x8;
typedef __attribute__((ext_vector_type(4))) float f32x4;

#define CHUNK 2048   // edges per bin_hist/bin_scatter block

__device__ inline unsigned short f2bf(float f) {   // RNE f32 -> bf16
  unsigned int u = __float_as_uint(f);
  u += 0x7fffu + ((u >> 16) & 1u);
  return (unsigned short)(u >> 16);
}

// Block-local int64-layout detect: hi words of first 2048 edges all zero.
__device__ inline int detect_use64(const int* __restrict__ ei, int t,
                                   int* __restrict__ lds_flag) {
  if (t == 0) *lds_flag = 0;
  __syncthreads();
  int acc = 0;
#pragma unroll
  for (int it = 0; it < 8; ++it) acc |= ei[2 * (t + (it << 8)) + 1];
  if (acc != 0) atomicOr(lds_flag, 1);
  __syncthreads();
  return (*lds_flag == 0) ? 1 : 0;
}

// Blocks [0,NBLK): LDS histogram of bucket=dst>>7 -> mat[b][blk].
// Blocks [NBLK,NBLK+160): transpose+convert W1/W2/W3. Block 0 zeroes ctrs.
__global__ __launch_bounds__(256)
void bin_hist_prep(const int* __restrict__ ei, int* __restrict__ mat,
                   int E, int NB, int NBLK,
                   const float* __restrict__ W1, const float* __restrict__ W2,
                   const float* __restrict__ W3, unsigned short* __restrict__ Wt1,
                   unsigned short* __restrict__ Wt2, unsigned short* __restrict__ Wt3,
                   int* __restrict__ ctr) {
  const int t = threadIdx.x;
  const int bid = blockIdx.x;
  if (bid == 0 && t < 3) ctr[t] = 0;
  if (bid >= NBLK) {
    const int idx = (bid - NBLK) * 256 + t;
    if (idx < 16384) {
      const int m = idx >> 7, k = idx & 127;
      Wt1[idx] = f2bf(W1[k * 128 + m]);
    } else if (idx < 32768) {
      const int l = idx - 16384;
      const int m = l >> 7, k = l & 127;
      Wt2[l] = f2bf(W2[k * 128 + m]);
    } else if (idx < 40960) {
      const int l = idx - 32768;
      const int m = l >> 7, k = l & 127;
      Wt3[l] = f2bf(W3[k * 64 + m]);
    }
    return;
  }
  __shared__ int hist[1024];
  __shared__ int lflag;
  const int use64 = detect_use64(ei, t, &lflag);
  for (int i = t; i < NB; i += 256) hist[i] = 0;
  __syncthreads();
  const int base = bid * CHUNK;
#pragma unroll
  for (int it = 0; it < CHUNK / 256; ++it) {
    const int e = base + t + it * 256;
    if (e < E) {
      const int d = use64 ? ei[2 * (E + e)] : ei[E + e];
      atomicAdd(&hist[d >> 7], 1);
    }
  }
  __syncthreads();
  for (int i = t; i < NB; i += 256) mat[i * NBLK + bid] = hist[i];
}

// Scan phase 1: per-1024-chunk block sums of mat -> bsums (raw).
__global__ __launch_bounds__(256)
void scan_phase1(const int* __restrict__ mat, int* __restrict__ bsums, int L) {
  __shared__ int red[256];
  const int t = threadIdx.x;
  const int base = blockIdx.x * 1024 + t * 4;
  int s = 0;
#pragma unroll
  for (int j = 0; j < 4; ++j)
    if (base + j < L) s += mat[base + j];
  red[t] = s;
  __syncthreads();
  for (int off = 128; off > 0; off >>= 1) {
    if (t < off) red[t] += red[t + off];
    __syncthreads();
  }
  if (t == 0) bsums[blockIdx.x] = red[0];
}

// Merged phase 2+3: each block re-scans raw bsums in LDS (SB <= 1024) to get
// its exclusive prefix, then scans its own 1024 mat entries -> global offsets.
// Block 0 also writes row_start[N] = E.
__global__ __launch_bounds__(256)
void scan_phase3m(int* __restrict__ mat, const int* __restrict__ bsums,
                  int* __restrict__ row_start, int SB, int L, int N) {
  __shared__ int sb[1024];
  __shared__ int tsum[256];
  const int t = threadIdx.x;
  const int bid = blockIdx.x;
#pragma unroll
  for (int j = 0; j < 4; ++j) {
    const int idx = t + j * 256;
    sb[idx] = (idx < SB) ? bsums[idx] : 0;
  }
  __syncthreads();
  for (int off = 1; off < 1024; off <<= 1) {
    int tmp[4];
#pragma unroll
    for (int j = 0; j < 4; ++j) {
      const int idx = t + j * 256;
      tmp[j] = (idx >= off) ? sb[idx - off] : 0;
    }
    __syncthreads();
#pragma unroll
    for (int j = 0; j < 4; ++j) sb[t + j * 256] += tmp[j];
    __syncthreads();
  }
  const int base0 = (bid == 0) ? 0 : sb[bid - 1];   // exclusive prefix
  if (bid == 0 && t == 0) row_start[N] = sb[SB - 1];  // total = E
  const int base = bid * 1024 + t * 4;
  int v[4];
#pragma unroll
  for (int j = 0; j < 4; ++j) v[j] = (base + j < L) ? mat[base + j] : 0;
  const int tot = v[0] + v[1] + v[2] + v[3];
  tsum[t] = tot;
  __syncthreads();
  for (int off = 1; off < 256; off <<= 1) {
    const int add = (t >= off) ? tsum[t - off] : 0;
    __syncthreads();
    tsum[t] += add;
    __syncthreads();
  }
  int run = base0 + tsum[t] - tot;
#pragma unroll
  for (int j = 0; j < 4; ++j) {
    if (base + j < L) { mat[base + j] = run; run += v[j]; }
  }
}

// Scatter edges to bucket-major order; rank via LDS atomics only.
__global__ __launch_bounds__(256)
void bin_scatter(const int* __restrict__ ei, const float* __restrict__ ew,
                 const int* __restrict__ mat, int2* __restrict__ binned,
                 int E, int NB, int NBLK) {
  __shared__ int boff[1024];
  __shared__ int cur[1024];
  __shared__ int lflag;
  const int t = threadIdx.x;
  const int use64 = detect_use64(ei, t, &lflag);
  for (int i = t; i < NB; i += 256) {
    boff[i] = mat[i * NBLK + blockIdx.x];
    cur[i] = 0;
  }
  __syncthreads();
  const int base = blockIdx.x * CHUNK;
#pragma unroll
  for (int it = 0; it < CHUNK / 256; ++it) {
    const int e = base + t + it * 256;
    if (e < E) {
      const int s = use64 ? ei[2 * e] : ei[e];
      const int d = use64 ? ei[2 * (E + e)] : ei[E + e];
      const int b = d >> 7;
      const int r = atomicAdd(&cur[b], 1);
      binned[boff[b] + r] = make_int2(s | ((d & 127) << 17), __float_as_int(ew[e]));
    }
  }
}

// One block per 128-node bucket: per-node counts + fixed24 deg sums (LDS),
// local scan -> row_start, dis; then scatter into final node-order CSR with
// dis[dst] folded into the stored weight.
__global__ __launch_bounds__(512)
void bucket_finalize(const int2* __restrict__ binned, const int* __restrict__ mat,
                     int* __restrict__ row_start, float* __restrict__ dis,
                     int2* __restrict__ csr, int E, int N, int NB, int NBLK) {
  __shared__ int cnt[128];
  __shared__ unsigned int fxs[128];
  __shared__ int sc[128];
  __shared__ int rowb[128];
  __shared__ float disl[128];
  __shared__ int cur[128];
  const int t = threadIdx.x;
  const int b = blockIdx.x;
  const int beg = mat[b * NBLK];
  const int end = (b == NB - 1) ? E : mat[(b + 1) * NBLK];
  if (t < 128) { cnt[t] = 0; fxs[t] = 0u; }
  __syncthreads();
  for (int i = beg + t; i < end; i += 512) {
    const int2 r = binned[i];
    const int dl = (r.x >> 17) & 127;
    atomicAdd(&cnt[dl], 1);
    atomicAdd(&fxs[dl], (unsigned int)(__int_as_float(r.y) * 16777216.0f));
  }
  __syncthreads();
  if (t < 128) sc[t] = cnt[t];
  __syncthreads();
  for (int off = 1; off < 128; off <<= 1) {
    const int v = (t < 128 && t >= off) ? sc[t - off] : 0;
    __syncthreads();
    if (t < 128) sc[t] += v;
    __syncthreads();
  }
  if (t < 128) {
    const int node = (b << 7) + t;
    const int rb = beg + sc[t] - cnt[t];   // exclusive
    rowb[t] = rb;
    cur[t] = 0;
    if (node < N) {
      row_start[node] = rb;
      const float deg = (float)fxs[t] * (1.0f / 16777216.0f);
      const float di = rsqrtf(deg + 1.0f);
      dis[node] = di;
      disl[t] = di;
    }
  }
  __syncthreads();
  for (int i = beg + t; i < end; i += 512) {
    const int2 r = binned[i];
    const int dl = (r.x >> 17) & 127;
    const int rk = atomicAdd(&cur[dl], 1);
    csr[rowb[dl] + rk] =
        make_int2(r.x & 0x1FFFF, __float_as_int(__int_as_float(r.y) * disl[dl]));
  }
}

// C[N x M] = dis[row] * (A[N x 128] @ B[128 x M]) via 16x16x32 bf16 MFMA.
// AF32: A is f32 (layer 1 reads x directly, converts in-register).
template <int M, bool AF32>
__global__ __launch_bounds__(256)
void gemm_mfma(const void* __restrict__ Ap, const unsigned short* __restrict__ Bt,
               const float* __restrict__ dis, unsigned short* __restrict__ C, int N) {
  const int lane = threadIdx.x & 63;
  const int m = lane & 15;
  const int q = lane >> 4;
  const int row0 = (blockIdx.x << 6) + ((threadIdx.x >> 6) << 4);

  const bool rowok = (row0 + m) < N;
  bf16x8 a[4];
  const bf16x8 zf = {0, 0, 0, 0, 0, 0, 0, 0};
  if (AF32) {
    const float* arow = (const float*)Ap + (long long)(row0 + m) * 128 + q * 8;
#pragma unroll
    for (int kt = 0; kt < 4; ++kt) {
      if (rowok) {
        const float4 v0 = *(const float4*)(arow + kt * 32);
        const float4 v1 = *(const float4*)(arow + kt * 32 + 4);
        bf16x8 av;
        av[0] = (short)f2bf(v0.x); av[1] = (short)f2bf(v0.y);
        av[2] = (short)f2bf(v0.z); av[3] = (short)f2bf(v0.w);
        av[4] = (short)f2bf(v1.x); av[5] = (short)f2bf(v1.y);
        av[6] = (short)f2bf(v1.z); av[7] = (short)f2bf(v1.w);
        a[kt] = av;
      } else {
        a[kt] = zf;
      }
    }
  } else {
    const unsigned short* arow =
        (const unsigned short*)Ap + (long long)(row0 + m) * 128 + q * 8;
#pragma unroll
    for (int kt = 0; kt < 4; ++kt)
      a[kt] = rowok ? *(const bf16x8*)(arow + kt * 32) : zf;
  }

#pragma unroll
  for (int ct = 0; ct < M / 16; ++ct) {
    f32x4 acc = {0.f, 0.f, 0.f, 0.f};
    const unsigned short* brow = Bt + (ct * 16 + m) * 128 + q * 8;
#pragma unroll
    for (int kt = 0; kt < 4; ++kt) {
      const bf16x8 b = *(const bf16x8*)(brow + kt * 32);
      acc = __builtin_amdgcn_mfma_f32_16x16x32_bf16(a[kt], b, acc, 0, 0, 0);
    }
#pragma unroll
    for (int r = 0; r < 4; ++r) {
      const int row = row0 + q * 4 + r;
      if (row < N) {
        const float sc = dis[row];
        C[(long long)row * M + ct * 16 + m] = f2bf(acc[r] * sc);
      }
    }
  }
}

// Persistent-wave gather: each wave pulls nodes from a global counter
// (removes Poisson-degree tail imbalance). csr entries wave-uniform ->
// scalar loads; row loads VMEM; rows pre-scaled by dis[src].
template <int M, bool RELU, bool OUTBF>
__global__ __launch_bounds__(256)
void gather(const int2* __restrict__ csr, const int* __restrict__ row_start,
            const unsigned short* __restrict__ xw, const float* __restrict__ dis,
            const float* __restrict__ bias, void* __restrict__ outp,
            int* __restrict__ ctr, int N) {
  const int lane = threadIdx.x & 63;
  for (;;) {
    int n0 = 0;
    if (lane == 0) n0 = atomicAdd(ctr, 1);
    const int node = __shfl(n0, 0);
    if (node >= N) return;
    const int beg = __builtin_amdgcn_readfirstlane(row_start[node]);
    const int end = __builtin_amdgcn_readfirstlane(row_start[node + 1]);
    if (M == 128) {
      const int c = lane << 1;
      float2 a0 = make_float2(0.f, 0.f), a1 = a0, a2 = a0, a3 = a0;
      int e = beg;
      for (; e + 15 < end; e += 16) {
        int2 p[16];
        unsigned int u[16];
#pragma unroll
        for (int j = 0; j < 16; ++j) p[j] = csr[e + j];
#pragma unroll
        for (int j = 0; j < 16; ++j)
          u[j] = *(const unsigned int*)(xw + (long long)p[j].x * 128 + c);
#pragma unroll
        for (int j = 0; j < 16; ++j) {
          const float nm = __int_as_float(p[j].y);
          float2& ac = (j & 2) ? ((j & 1) ? a3 : a2) : ((j & 1) ? a1 : a0);
          ac.x = fmaf(nm, __uint_as_float(u[j] << 16), ac.x);
          ac.y = fmaf(nm, __uint_as_float(u[j] & 0xffff0000u), ac.y);
        }
      }
      for (; e + 7 < end; e += 8) {
        int2 p[8];
        unsigned int u[8];
#pragma unroll
        for (int j = 0; j < 8; ++j) p[j] = csr[e + j];
#pragma unroll
        for (int j = 0; j < 8; ++j)
          u[j] = *(const unsigned int*)(xw + (long long)p[j].x * 128 + c);
#pragma unroll
        for (int j = 0; j < 8; ++j) {
          const float nm = __int_as_float(p[j].y);
          float2& ac = (j & 2) ? ((j & 1) ? a3 : a2) : ((j & 1) ? a1 : a0);
          ac.x = fmaf(nm, __uint_as_float(u[j] << 16), ac.x);
          ac.y = fmaf(nm, __uint_as_float(u[j] & 0xffff0000u), ac.y);
        }
      }
      for (; e + 1 < end; e += 2) {
        const int2 p0 = csr[e], p1 = csr[e + 1];
        const unsigned int u0 = *(const unsigned int*)(xw + (long long)p0.x * 128 + c);
        const unsigned int u1 = *(const unsigned int*)(xw + (long long)p1.x * 128 + c);
        const float n0f = __int_as_float(p0.y), n1f = __int_as_float(p1.y);
        a0.x = fmaf(n0f, __uint_as_float(u0 << 16), a0.x);
        a0.y = fmaf(n0f, __uint_as_float(u0 & 0xffff0000u), a0.y);
        a1.x = fmaf(n1f, __uint_as_float(u1 << 16), a1.x);
        a1.y = fmaf(n1f, __uint_as_float(u1 & 0xffff0000u), a1.y);
      }
      if (e < end) {
        const int2 p = csr[e];
        const float nm = __int_as_float(p.y);
        const unsigned int u = *(const unsigned int*)(xw + (long long)p.x * 128 + c);
        a2.x = fmaf(nm, __uint_as_float(u << 16), a2.x);
        a2.y = fmaf(nm, __uint_as_float(u & 0xffff0000u), a2.y);
      }
      float2 acc;
      acc.x = (a0.x + a1.x) + (a2.x + a3.x);
      acc.y = (a0.y + a1.y) + (a2.y + a3.y);
      const float di = dis[node];
      const unsigned int su = *(const unsigned int*)(xw + (long long)node * 128 + c);
      const float2 bv = *(const float2*)(bias + c);
      acc.x = fmaf(di, __uint_as_float(su << 16), acc.x) + bv.x;
      acc.y = fmaf(di, __uint_as_float(su & 0xffff0000u), acc.y) + bv.y;
      if (RELU) { acc.x = fmaxf(acc.x, 0.f); acc.y = fmaxf(acc.y, 0.f); }
      if (OUTBF) {
        const unsigned int pk =
            (unsigned int)f2bf(acc.x) | ((unsigned int)f2bf(acc.y) << 16);
        ((unsigned int*)outp)[(long long)node * 64 + lane] = pk;
      } else {
        *(float2*)((float*)outp + (long long)node * 128 + c) = acc;
      }
    } else {
      float a0 = 0.f, a1 = 0.f, a2 = 0.f, a3 = 0.f;
      int e = beg;
      for (; e + 15 < end; e += 16) {
        int2 p[16];
        unsigned int v[16];
#pragma unroll
        for (int j = 0; j < 16; ++j) p[j] = csr[e + j];
#pragma unroll
        for (int j = 0; j < 16; ++j) v[j] = xw[(long long)p[j].x * 64 + lane];
#pragma unroll
        for (int j = 0; j < 16; ++j) {
          float& ac = (j & 2) ? ((j & 1) ? a3 : a2) : ((j & 1) ? a1 : a0);
          ac = fmaf(__int_as_float(p[j].y), __uint_as_float(v[j] << 16), ac);
        }
      }
      for (; e + 7 < end; e += 8) {
        int2 p[8];
        unsigned int v[8];
#pragma unroll
        for (int j = 0; j < 8; ++j) p[j] = csr[e + j];
#pragma unroll
        for (int j = 0; j < 8; ++j) v[j] = xw[(long long)p[j].x * 64 + lane];
#pragma unroll
        for (int j = 0; j < 8; ++j) {
          float& ac = (j & 2) ? ((j & 1) ? a3 : a2) : ((j & 1) ? a1 : a0);
          ac = fmaf(__int_as_float(p[j].y), __uint_as_float(v[j] << 16), ac);
        }
      }
      for (; e < end; ++e) {
        const int2 p = csr[e];
        const unsigned int v = xw[(long long)p.x * 64 + lane];
        a0 = fmaf(__int_as_float(p.y), __uint_as_float(v << 16), a0);
      }
      float acc = (a0 + a1) + (a2 + a3);
      const float di = dis[node];
      const unsigned int sv = xw[(long long)node * 64 + lane];
      float r = fmaf(di, __uint_as_float(sv << 16), acc) + bias[lane];
      if (RELU) r = fmaxf(r, 0.f);
      ((float*)outp)[(long long)node * 64 + lane] = r;
    }
  }
}

extern "C" void kernel_launch(void* const* d_in, const int* in_sizes, int n_in,
                              void* d_out, int out_size, void* d_ws, size_t ws_size,
                              hipStream_t stream) {
  const float* x  = (const float*)d_in[0];
  const int*   ei = (const int*)d_in[1];
  const float* ew = (const float*)d_in[2];
  const float* W1 = (const float*)d_in[3];
  const float* b1 = (const float*)d_in[4];
  const float* W2 = (const float*)d_in[5];
  const float* b2 = (const float*)d_in[6];
  const float* W3 = (const float*)d_in[7];
  const float* b3 = (const float*)d_in[8];
  float* out = (float*)d_out;

  const int IN = 128;
  const int N = in_sizes[0] / IN;   // 100000
  const int E = in_sizes[2];        // 1600000

  char* ws = (char*)d_ws;
  float* dis       = (float*)(ws + (1u << 20));
  int*   ctr       = (int*)(ws + (1472u << 10));
  int*   bsums     = (int*)(ws + (1536u << 10));
  int*   row_start = (int*)(ws + (1600u << 10));
  int2*  csr       = (int2*)(ws + (2560u << 10));
  unsigned short* Wt1 = (unsigned short*)(ws + (15872u << 10));
  unsigned short* Wt2 = (unsigned short*)(ws + (15872u << 10) + (128u << 10));
  unsigned short* Wt3 = (unsigned short*)(ws + (15872u << 10) + (256u << 10));
  unsigned short* bufA = (unsigned short*)(ws + (16u << 20));   // bf16 xw'
  unsigned short* hbf  = (unsigned short*)(ws + (42u << 20));   // bf16 h1/h2
  int*   mat    = (int*)(ws + (68u << 20));     // NB x NBLK offsets (2.45 MB)
  int2*  binned = (int2*)(ws + (71u << 20));    // bucket-major COO (12.8 MB)

  const dim3 blk(256);
  const int NB = (N + 127) >> 7;                 // 782 buckets of 128 nodes
  const int NBLK = (E + CHUNK - 1) / CHUNK;      // 782 edge chunks
  const int L = NB * NBLK;                       // ~611K
  const int SB = (L + 1023) / 1024;              // 598 (<= 1024)

  // --- atomic-free CSR build (5 kernels) ---
  hipLaunchKernelGGL(bin_hist_prep, dim3(NBLK + 160), blk, 0, stream,
                     ei, mat, E, NB, NBLK, W1, W2, W3, Wt1, Wt2, Wt3, ctr);
  hipLaunchKernelGGL(scan_phase1, dim3(SB), blk, 0, stream, mat, bsums, L);
  hipLaunchKernelGGL(scan_phase3m, dim3(SB), blk, 0, stream, mat, bsums,
                     row_start, SB, L, N);
  hipLaunchKernelGGL(bin_scatter, dim3(NBLK), blk, 0, stream, ei, ew, mat,
                     binned, E, NB, NBLK);
  hipLaunchKernelGGL(bucket_finalize, dim3(NB), dim3(512), 0, stream, binned, mat,
                     row_start, dis, csr, E, N, NB, NBLK);

  const int gGemm = (N + 63) / 64;
  const int gGather = 2048;   // persistent waves (8 blocks/CU)

  // --- layer 1 (GEMM reads f32 x directly) ---
  hipLaunchKernelGGL((gemm_mfma<128, true>), dim3(gGemm), blk, 0, stream,
                     (const void*)x, Wt1, dis, bufA, N);
  hipLaunchKernelGGL((gather<128, true, true>), dim3(gGather), blk, 0, stream,
                     csr, row_start, bufA, dis, b1, hbf, ctr + 0, N);
  // --- layer 2 ---
  hipLaunchKernelGGL((gemm_mfma<128, false>), dim3(gGemm), blk, 0, stream,
                     (const void*)hbf, Wt2, dis, bufA, N);
  hipLaunchKernelGGL((gather<128, true, true>), dim3(gGather), blk, 0, stream,
                     csr, row_start, bufA, dis, b2, hbf, ctr + 1, N);
  // --- layer 3 ---
  hipLaunchKernelGGL((gemm_mfma<64, false>), dim3(gGemm), blk, 0, stream,
                     (const void*)hbf, Wt3, dis, bufA, N);
  hipLaunchKernelGGL((gather<64, false, false>), dim3(gGather), blk, 0, stream,
                     csr, row_start, bufA, dis, b3, out, ctr + 2, N);
}

// Round 11
// 433.297 us; speedup vs baseline: 9.1416x; 9.1416x over previous
//
#include <hip/hip_runtime.h>

// ---------------------------------------------------------------------------
// GCN 3-layer forward. CSR-gather + bf16 MFMA GEMM.
// R2: atomic-free CSR build (LDS-ranked 2-level counting sort).
// R3-R6: gather<128> floor = 61us static (L2-miss/L3-fabric bound: 200MB
//     L2-miss @ 3.3TB/s; unroll/occupancy/dep-chain all neutral).
//     dis[src] folded into GEMM epilogue.
// R7: CHUNK 2048 + 512-thr finalize — 435us. R8: coop grid.sync — 13x
//     REGRESSION (~100us/sync across 8 XCDs). R9: x->bf16 fused into GEMM1
//     (AF32) — neutral, kept. R10: dynamic-counter gather — 9x REGRESSION:
//     same-address device RMW ~28cy each, device-wide serial (1185us for
//     100K). Lesson: no cross-XCD serialization points on MI355X.
// R11: revert gather to R9 static form; keep R10's neutral launch fusions
//     (scan_phase2 merged into phase3; prep_w fused into bin_hist grid).
// d_ws layout (max ~84 MB used; 119.2 MB proven safe):
//   [1 MB)   dis: N floats
//   [1.5 MB) bsums: up to 1024 ints
//   [1.6 MB) row_start: (N+1) ints
//   [2.5 MB) csr: E x int2 {src, ew*dis[dst] as float}  (12.8 MB)
//   [15.5MB) Wt1 bf16 [128][128]; Wt2; Wt3 [64][128]
//   [16 MB)  bufA: N*128 bf16 xw' (25.6 MB)
//   [42 MB)  hbf: N*128 bf16 (h1_bf16, then h2_bf16)
//   [68 MB)  mat: NB x NBLK ints (bucket-major count/offset matrix, 2.45 MB)
//   [71 MB)  binned: E x int2 {src | dstlow<<17, ew}  (12.8 MB, ends 83.8 MB)
// ---------------------------------------------------------------------------

typedef __attribute__((ext_vector_type(8))) short bf16x8;
typedef __attribute__((ext_vector_type(4))) float f32x4;

#define CHUNK 2048   // edges per bin_hist/bin_scatter block

__device__ inline unsigned short f2bf(float f) {   // RNE f32 -> bf16
  unsigned int u = __float_as_uint(f);
  u += 0x7fffu + ((u >> 16) & 1u);
  return (unsigned short)(u >> 16);
}

// Block-local int64-layout detect: hi words of first 2048 edges all zero.
__device__ inline int detect_use64(const int* __restrict__ ei, int t,
                                   int* __restrict__ lds_flag) {
  if (t == 0) *lds_flag = 0;
  __syncthreads();
  int acc = 0;
#pragma unroll
  for (int it = 0; it < 8; ++it) acc |= ei[2 * (t + (it << 8)) + 1];
  if (acc != 0) atomicOr(lds_flag, 1);
  __syncthreads();
  return (*lds_flag == 0) ? 1 : 0;
}

// Blocks [0,NBLK): LDS histogram of bucket=dst>>7 -> mat[b][blk].
// Blocks [NBLK,NBLK+160): transpose+convert W1/W2/W3.
__global__ __launch_bounds__(256)
void bin_hist_prep(const int* __restrict__ ei, int* __restrict__ mat,
                   int E, int NB, int NBLK,
                   const float* __restrict__ W1, const float* __restrict__ W2,
                   const float* __restrict__ W3, unsigned short* __restrict__ Wt1,
                   unsigned short* __restrict__ Wt2, unsigned short* __restrict__ Wt3) {
  const int t = threadIdx.x;
  const int bid = blockIdx.x;
  if (bid >= NBLK) {
    const int idx = (bid - NBLK) * 256 + t;
    if (idx < 16384) {
      const int m = idx >> 7, k = idx & 127;
      Wt1[idx] = f2bf(W1[k * 128 + m]);
    } else if (idx < 32768) {
      const int l = idx - 16384;
      const int m = l >> 7, k = l & 127;
      Wt2[l] = f2bf(W2[k * 128 + m]);
    } else if (idx < 40960) {
      const int l = idx - 32768;
      const int m = l >> 7, k = l & 127;
      Wt3[l] = f2bf(W3[k * 64 + m]);
    }
    return;
  }
  __shared__ int hist[1024];
  __shared__ int lflag;
  const int use64 = detect_use64(ei, t, &lflag);
  for (int i = t; i < NB; i += 256) hist[i] = 0;
  __syncthreads();
  const int base = bid * CHUNK;
#pragma unroll
  for (int it = 0; it < CHUNK / 256; ++it) {
    const int e = base + t + it * 256;
    if (e < E) {
      const int d = use64 ? ei[2 * (E + e)] : ei[E + e];
      atomicAdd(&hist[d >> 7], 1);
    }
  }
  __syncthreads();
  for (int i = t; i < NB; i += 256) mat[i * NBLK + bid] = hist[i];
}

// Scan phase 1: per-1024-chunk block sums of mat -> bsums (raw).
__global__ __launch_bounds__(256)
void scan_phase1(const int* __restrict__ mat, int* __restrict__ bsums, int L) {
  __shared__ int red[256];
  const int t = threadIdx.x;
  const int base = blockIdx.x * 1024 + t * 4;
  int s = 0;
#pragma unroll
  for (int j = 0; j < 4; ++j)
    if (base + j < L) s += mat[base + j];
  red[t] = s;
  __syncthreads();
  for (int off = 128; off > 0; off >>= 1) {
    if (t < off) red[t] += red[t + off];
    __syncthreads();
  }
  if (t == 0) bsums[blockIdx.x] = red[0];
}

// Merged phase 2+3: each block re-scans raw bsums in LDS (SB <= 1024) to get
// its exclusive prefix, then scans its own 1024 mat entries -> global offsets.
// Block 0 also writes row_start[N] = E.
__global__ __launch_bounds__(256)
void scan_phase3m(int* __restrict__ mat, const int* __restrict__ bsums,
                  int* __restrict__ row_start, int SB, int L, int N) {
  __shared__ int sb[1024];
  __shared__ int tsum[256];
  const int t = threadIdx.x;
  const int bid = blockIdx.x;
#pragma unroll
  for (int j = 0; j < 4; ++j) {
    const int idx = t + j * 256;
    sb[idx] = (idx < SB) ? bsums[idx] : 0;
  }
  __syncthreads();
  for (int off = 1; off < 1024; off <<= 1) {
    int tmp[4];
#pragma unroll
    for (int j = 0; j < 4; ++j) {
      const int idx = t + j * 256;
      tmp[j] = (idx >= off) ? sb[idx - off] : 0;
    }
    __syncthreads();
#pragma unroll
    for (int j = 0; j < 4; ++j) sb[t + j * 256] += tmp[j];
    __syncthreads();
  }
  const int base0 = (bid == 0) ? 0 : sb[bid - 1];   // exclusive prefix
  if (bid == 0 && t == 0) row_start[N] = sb[SB - 1];  // total = E
  const int base = bid * 1024 + t * 4;
  int v[4];
#pragma unroll
  for (int j = 0; j < 4; ++j) v[j] = (base + j < L) ? mat[base + j] : 0;
  const int tot = v[0] + v[1] + v[2] + v[3];
  tsum[t] = tot;
  __syncthreads();
  for (int off = 1; off < 256; off <<= 1) {
    const int add = (t >= off) ? tsum[t - off] : 0;
    __syncthreads();
    tsum[t] += add;
    __syncthreads();
  }
  int run = base0 + tsum[t] - tot;
#pragma unroll
  for (int j = 0; j < 4; ++j) {
    if (base + j < L) { mat[base + j] = run; run += v[j]; }
  }
}

// Scatter edges to bucket-major order; rank via LDS atomics only.
__global__ __launch_bounds__(256)
void bin_scatter(const int* __restrict__ ei, const float* __restrict__ ew,
                 const int* __restrict__ mat, int2* __restrict__ binned,
                 int E, int NB, int NBLK) {
  __shared__ int boff[1024];
  __shared__ int cur[1024];
  __shared__ int lflag;
  const int t = threadIdx.x;
  const int use64 = detect_use64(ei, t, &lflag);
  for (int i = t; i < NB; i += 256) {
    boff[i] = mat[i * NBLK + blockIdx.x];
    cur[i] = 0;
  }
  __syncthreads();
  const int base = blockIdx.x * CHUNK;
#pragma unroll
  for (int it = 0; it < CHUNK / 256; ++it) {
    const int e = base + t + it * 256;
    if (e < E) {
      const int s = use64 ? ei[2 * e] : ei[e];
      const int d = use64 ? ei[2 * (E + e)] : ei[E + e];
      const int b = d >> 7;
      const int r = atomicAdd(&cur[b], 1);
      binned[boff[b] + r] = make_int2(s | ((d & 127) << 17), __float_as_int(ew[e]));
    }
  }
}

// One block per 128-node bucket: per-node counts + fixed24 deg sums (LDS),
// local scan -> row_start, dis; then scatter into final node-order CSR with
// dis[dst] folded into the stored weight.
__global__ __launch_bounds__(512)
void bucket_finalize(const int2* __restrict__ binned, const int* __restrict__ mat,
                     int* __restrict__ row_start, float* __restrict__ dis,
                     int2* __restrict__ csr, int E, int N, int NB, int NBLK) {
  __shared__ int cnt[128];
  __shared__ unsigned int fxs[128];
  __shared__ int sc[128];
  __shared__ int rowb[128];
  __shared__ float disl[128];
  __shared__ int cur[128];
  const int t = threadIdx.x;
  const int b = blockIdx.x;
  const int beg = mat[b * NBLK];
  const int end = (b == NB - 1) ? E : mat[(b + 1) * NBLK];
  if (t < 128) { cnt[t] = 0; fxs[t] = 0u; }
  __syncthreads();
  for (int i = beg + t; i < end; i += 512) {
    const int2 r = binned[i];
    const int dl = (r.x >> 17) & 127;
    atomicAdd(&cnt[dl], 1);
    atomicAdd(&fxs[dl], (unsigned int)(__int_as_float(r.y) * 16777216.0f));
  }
  __syncthreads();
  if (t < 128) sc[t] = cnt[t];
  __syncthreads();
  for (int off = 1; off < 128; off <<= 1) {
    const int v = (t < 128 && t >= off) ? sc[t - off] : 0;
    __syncthreads();
    if (t < 128) sc[t] += v;
    __syncthreads();
  }
  if (t < 128) {
    const int node = (b << 7) + t;
    const int rb = beg + sc[t] - cnt[t];   // exclusive
    rowb[t] = rb;
    cur[t] = 0;
    if (node < N) {
      row_start[node] = rb;
      const float deg = (float)fxs[t] * (1.0f / 16777216.0f);
      const float di = rsqrtf(deg + 1.0f);
      dis[node] = di;
      disl[t] = di;
    }
  }
  __syncthreads();
  for (int i = beg + t; i < end; i += 512) {
    const int2 r = binned[i];
    const int dl = (r.x >> 17) & 127;
    const int rk = atomicAdd(&cur[dl], 1);
    csr[rowb[dl] + rk] =
        make_int2(r.x & 0x1FFFF, __float_as_int(__int_as_float(r.y) * disl[dl]));
  }
}

// C[N x M] = dis[row] * (A[N x 128] @ B[128 x M]) via 16x16x32 bf16 MFMA.
// AF32: A is f32 (layer 1 reads x directly, converts in-register).
template <int M, bool AF32>
__global__ __launch_bounds__(256)
void gemm_mfma(const void* __restrict__ Ap, const unsigned short* __restrict__ Bt,
               const float* __restrict__ dis, unsigned short* __restrict__ C, int N) {
  const int lane = threadIdx.x & 63;
  const int m = lane & 15;
  const int q = lane >> 4;
  const int row0 = (blockIdx.x << 6) + ((threadIdx.x >> 6) << 4);

  const bool rowok = (row0 + m) < N;
  bf16x8 a[4];
  const bf16x8 zf = {0, 0, 0, 0, 0, 0, 0, 0};
  if (AF32) {
    const float* arow = (const float*)Ap + (long long)(row0 + m) * 128 + q * 8;
#pragma unroll
    for (int kt = 0; kt < 4; ++kt) {
      if (rowok) {
        const float4 v0 = *(const float4*)(arow + kt * 32);
        const float4 v1 = *(const float4*)(arow + kt * 32 + 4);
        bf16x8 av;
        av[0] = (short)f2bf(v0.x); av[1] = (short)f2bf(v0.y);
        av[2] = (short)f2bf(v0.z); av[3] = (short)f2bf(v0.w);
        av[4] = (short)f2bf(v1.x); av[5] = (short)f2bf(v1.y);
        av[6] = (short)f2bf(v1.z); av[7] = (short)f2bf(v1.w);
        a[kt] = av;
      } else {
        a[kt] = zf;
      }
    }
  } else {
    const unsigned short* arow =
        (const unsigned short*)Ap + (long long)(row0 + m) * 128 + q * 8;
#pragma unroll
    for (int kt = 0; kt < 4; ++kt)
      a[kt] = rowok ? *(const bf16x8*)(arow + kt * 32) : zf;
  }

#pragma unroll
  for (int ct = 0; ct < M / 16; ++ct) {
    f32x4 acc = {0.f, 0.f, 0.f, 0.f};
    const unsigned short* brow = Bt + (ct * 16 + m) * 128 + q * 8;
#pragma unroll
    for (int kt = 0; kt < 4; ++kt) {
      const bf16x8 b = *(const bf16x8*)(brow + kt * 32);
      acc = __builtin_amdgcn_mfma_f32_16x16x32_bf16(a[kt], b, acc, 0, 0, 0);
    }
#pragma unroll
    for (int r = 0; r < 4; ++r) {
      const int row = row0 + q * 4 + r;
      if (row < N) {
        const float sc = dis[row];
        C[(long long)row * M + ct * 16 + m] = f2bf(acc[r] * sc);
      }
    }
  }
}

// Static one-wave-per-node gather (R9 form — proven 61us floor).
// csr entries wave-uniform -> scalar loads; row loads VMEM, single dep chain.
template <int M, bool RELU, bool OUTBF>
__global__ __launch_bounds__(256)
void gather(const int2* __restrict__ csr, const int* __restrict__ row_start,
            const unsigned short* __restrict__ xw, const float* __restrict__ dis,
            const float* __restrict__ bias, void* __restrict__ outp, int N) {
  const int node = (blockIdx.x << 2) + (threadIdx.x >> 6);
  const int lane = threadIdx.x & 63;
  if (node >= N) return;
  const int beg = __builtin_amdgcn_readfirstlane(row_start[node]);
  const int end = __builtin_amdgcn_readfirstlane(row_start[node + 1]);
  if (M == 128) {
    const int c = lane << 1;
    float2 a0 = make_float2(0.f, 0.f), a1 = a0, a2 = a0, a3 = a0;
    int e = beg;
    for (; e + 15 < end; e += 16) {
      int2 p[16];
      unsigned int u[16];
#pragma unroll
      for (int j = 0; j < 16; ++j) p[j] = csr[e + j];
#pragma unroll
      for (int j = 0; j < 16; ++j)
        u[j] = *(const unsigned int*)(xw + (long long)p[j].x * 128 + c);
#pragma unroll
      for (int j = 0; j < 16; ++j) {
        const float nm = __int_as_float(p[j].y);
        float2& ac = (j & 2) ? ((j & 1) ? a3 : a2) : ((j & 1) ? a1 : a0);
        ac.x = fmaf(nm, __uint_as_float(u[j] << 16), ac.x);
        ac.y = fmaf(nm, __uint_as_float(u[j] & 0xffff0000u), ac.y);
      }
    }
    for (; e + 7 < end; e += 8) {
      int2 p[8];
      unsigned int u[8];
#pragma unroll
      for (int j = 0; j < 8; ++j) p[j] = csr[e + j];
#pragma unroll
      for (int j = 0; j < 8; ++j)
        u[j] = *(const unsigned int*)(xw + (long long)p[j].x * 128 + c);
#pragma unroll
      for (int j = 0; j < 8; ++j) {
        const float nm = __int_as_float(p[j].y);
        float2& ac = (j & 2) ? ((j & 1) ? a3 : a2) : ((j & 1) ? a1 : a0);
        ac.x = fmaf(nm, __uint_as_float(u[j] << 16), ac.x);
        ac.y = fmaf(nm, __uint_as_float(u[j] & 0xffff0000u), ac.y);
      }
    }
    for (; e + 1 < end; e += 2) {
      const int2 p0 = csr[e], p1 = csr[e + 1];
      const unsigned int u0 = *(const unsigned int*)(xw + (long long)p0.x * 128 + c);
      const unsigned int u1 = *(const unsigned int*)(xw + (long long)p1.x * 128 + c);
      const float n0 = __int_as_float(p0.y), n1 = __int_as_float(p1.y);
      a0.x = fmaf(n0, __uint_as_float(u0 << 16), a0.x);
      a0.y = fmaf(n0, __uint_as_float(u0 & 0xffff0000u), a0.y);
      a1.x = fmaf(n1, __uint_as_float(u1 << 16), a1.x);
      a1.y = fmaf(n1, __uint_as_float(u1 & 0xffff0000u), a1.y);
    }
    if (e < end) {
      const int2 p = csr[e];
      const float nm = __int_as_float(p.y);
      const unsigned int u = *(const unsigned int*)(xw + (long long)p.x * 128 + c);
      a2.x = fmaf(nm, __uint_as_float(u << 16), a2.x);
      a2.y = fmaf(nm, __uint_as_float(u & 0xffff0000u), a2.y);
    }
    float2 acc;
    acc.x = (a0.x + a1.x) + (a2.x + a3.x);
    acc.y = (a0.y + a1.y) + (a2.y + a3.y);
    const float di = dis[node];
    const unsigned int su = *(const unsigned int*)(xw + (long long)node * 128 + c);
    const float2 bv = *(const float2*)(bias + c);
    acc.x = fmaf(di, __uint_as_float(su << 16), acc.x) + bv.x;
    acc.y = fmaf(di, __uint_as_float(su & 0xffff0000u), acc.y) + bv.y;
    if (RELU) { acc.x = fmaxf(acc.x, 0.f); acc.y = fmaxf(acc.y, 0.f); }
    if (OUTBF) {
      const unsigned int pk =
          (unsigned int)f2bf(acc.x) | ((unsigned int)f2bf(acc.y) << 16);
      ((unsigned int*)outp)[(long long)node * 64 + lane] = pk;
    } else {
      *(float2*)((float*)outp + (long long)node * 128 + c) = acc;
    }
  } else {
    float a0 = 0.f, a1 = 0.f, a2 = 0.f, a3 = 0.f;
    int e = beg;
    for (; e + 15 < end; e += 16) {
      int2 p[16];
      unsigned int v[16];
#pragma unroll
      for (int j = 0; j < 16; ++j) p[j] = csr[e + j];
#pragma unroll
      for (int j = 0; j < 16; ++j) v[j] = xw[(long long)p[j].x * 64 + lane];
#pragma unroll
      for (int j = 0; j < 16; ++j) {
        float& ac = (j & 2) ? ((j & 1) ? a3 : a2) : ((j & 1) ? a1 : a0);
        ac = fmaf(__int_as_float(p[j].y), __uint_as_float(v[j] << 16), ac);
      }
    }
    for (; e + 7 < end; e += 8) {
      int2 p[8];
      unsigned int v[8];
#pragma unroll
      for (int j = 0; j < 8; ++j) p[j] = csr[e + j];
#pragma unroll
      for (int j = 0; j < 8; ++j) v[j] = xw[(long long)p[j].x * 64 + lane];
#pragma unroll
      for (int j = 0; j < 8; ++j) {
        float& ac = (j & 2) ? ((j & 1) ? a3 : a2) : ((j & 1) ? a1 : a0);
        ac = fmaf(__int_as_float(p[j].y), __uint_as_float(v[j] << 16), ac);
      }
    }
    for (; e < end; ++e) {
      const int2 p = csr[e];
      const unsigned int v = xw[(long long)p.x * 64 + lane];
      a0 = fmaf(__int_as_float(p.y), __uint_as_float(v << 16), a0);
    }
    float acc = (a0 + a1) + (a2 + a3);
    const float di = dis[node];
    const unsigned int sv = xw[(long long)node * 64 + lane];
    float r = fmaf(di, __uint_as_float(sv << 16), acc) + bias[lane];
    if (RELU) r = fmaxf(r, 0.f);
    ((float*)outp)[(long long)node * 64 + lane] = r;
  }
}

extern "C" void kernel_launch(void* const* d_in, const int* in_sizes, int n_in,
                              void* d_out, int out_size, void* d_ws, size_t ws_size,
                              hipStream_t stream) {
  const float* x  = (const float*)d_in[0];
  const int*   ei = (const int*)d_in[1];
  const float* ew = (const float*)d_in[2];
  const float* W1 = (const float*)d_in[3];
  const float* b1 = (const float*)d_in[4];
  const float* W2 = (const float*)d_in[5];
  const float* b2 = (const float*)d_in[6];
  const float* W3 = (const float*)d_in[7];
  const float* b3 = (const float*)d_in[8];
  float* out = (float*)d_out;

  const int IN = 128;
  const int N = in_sizes[0] / IN;   // 100000
  const int E = in_sizes[2];        // 1600000

  char* ws = (char*)d_ws;
  float* dis       = (float*)(ws + (1u << 20));
  int*   bsums     = (int*)(ws + (1536u << 10));
  int*   row_start = (int*)(ws + (1600u << 10));
  int2*  csr       = (int2*)(ws + (2560u << 10));
  unsigned short* Wt1 = (unsigned short*)(ws + (15872u << 10));
  unsigned short* Wt2 = (unsigned short*)(ws + (15872u << 10) + (128u << 10));
  unsigned short* Wt3 = (unsigned short*)(ws + (15872u << 10) + (256u << 10));
  unsigned short* bufA = (unsigned short*)(ws + (16u << 20));   // bf16 xw'
  unsigned short* hbf  = (unsigned short*)(ws + (42u << 20));   // bf16 h1/h2
  int*   mat    = (int*)(ws + (68u << 20));     // NB x NBLK offsets (2.45 MB)
  int2*  binned = (int2*)(ws + (71u << 20));    // bucket-major COO (12.8 MB)

  const dim3 blk(256);
  const int NB = (N + 127) >> 7;                 // 782 buckets of 128 nodes
  const int NBLK = (E + CHUNK - 1) / CHUNK;      // 782 edge chunks
  const int L = NB * NBLK;                       // ~611K
  const int SB = (L + 1023) / 1024;              // 598 (<= 1024)

  // --- atomic-free CSR build (5 kernels) ---
  hipLaunchKernelGGL(bin_hist_prep, dim3(NBLK + 160), blk, 0, stream,
                     ei, mat, E, NB, NBLK, W1, W2, W3, Wt1, Wt2, Wt3);
  hipLaunchKernelGGL(scan_phase1, dim3(SB), blk, 0, stream, mat, bsums, L);
  hipLaunchKernelGGL(scan_phase3m, dim3(SB), blk, 0, stream, mat, bsums,
                     row_start, SB, L, N);
  hipLaunchKernelGGL(bin_scatter, dim3(NBLK), blk, 0, stream, ei, ew, mat,
                     binned, E, NB, NBLK);
  hipLaunchKernelGGL(bucket_finalize, dim3(NB), dim3(512), 0, stream, binned, mat,
                     row_start, dis, csr, E, N, NB, NBLK);

  const int gGemm = (N + 63) / 64;
  const int gGather = (N + 3) / 4;

  // --- layer 1 (GEMM reads f32 x directly) ---
  hipLaunchKernelGGL((gemm_mfma<128, true>), dim3(gGemm), blk, 0, stream,
                     (const void*)x, Wt1, dis, bufA, N);
  hipLaunchKernelGGL((gather<128, true, true>), dim3(gGather), blk, 0, stream,
                     csr, row_start, bufA, dis, b1, hbf, N);
  // --- layer 2 ---
  hipLaunchKernelGGL((gemm_mfma<128, false>), dim3(gGemm), blk, 0, stream,
                     (const void*)hbf, Wt2, dis, bufA, N);
  hipLaunchKernelGGL((gather<128, true, true>), dim3(gGather), blk, 0, stream,
                     csr, row_start, bufA, dis, b2, hbf, N);
  // --- layer 3 ---
  hipLaunchKernelGGL((gemm_mfma<64, false>), dim3(gGemm), blk, 0, stream,
                     (const void*)hbf, Wt3, dis, bufA, N);
  hipLaunchKernelGGL((gather<64, false, false>), dim3(gGather), blk, 0, stream,
                     csr, row_start, bufA, dis, b3, out, N);
}